// Round 1
// baseline (183.819 us; speedup 1.0000x reference)
//
#include <hip/hip_runtime.h>

// Problem constants (B,C,H,W,K) = (32,192,56,56,7)
#define BB 32
#define CC 192
#define HH 56
#define WW 56
#define KS 7
#define HW 3136        // 56*56
#define KK 49          // 7*7
#define CKK 9408       // C*K*K
#define PL 8           // pool window H/K = W/K = 8
#define NCELL (BB * CC * KK)   // 301056 pool cells
#define NBC (BB * CC)          // 6144 (b,c) pairs

// ---------------------------------------------------------------------------
// Kernel 1: adaptive avg pool 56x56 -> 7x7 (uniform 8x8 mean)
// One thread per pool cell; 2 float4 loads per row x 8 rows (all 16B-aligned).
// ---------------------------------------------------------------------------
__global__ __launch_bounds__(256) void pool_kernel(const float* __restrict__ x,
                                                   float* __restrict__ p0) {
    int idx = blockIdx.x * 256 + threadIdx.x;
    if (idx >= NCELL) return;
    int j = idx % KS;
    int i = (idx / KS) % KS;
    int bc = idx / KK;
    const float* src = x + (size_t)bc * HW + (i * PL) * WW + j * PL;
    float s = 0.f;
#pragma unroll
    for (int a = 0; a < PL; ++a) {
        float4 v0 = *(const float4*)(src + a * WW);
        float4 v1 = *(const float4*)(src + a * WW + 4);
        s += v0.x + v0.y + v0.z + v0.w + v1.x + v1.y + v1.z + v1.w;
    }
    p0[idx] = s * (1.f / 64.f);
}

// ---------------------------------------------------------------------------
// Kernel 2: LN0 -> depthwise 7x7 conv (SAME) on the 7x7 map -> LN1 -> ReLU
// One block per sample b (reduction over all C*K*K per sample).
// ---------------------------------------------------------------------------
#define MT 512
#define MIT ((CKK + MT - 1) / MT)   // 19 iterations per thread

__device__ inline float2 block_reduce2(float s, float ss, float* red, int tid) {
#pragma unroll
    for (int o = 32; o > 0; o >>= 1) {
        s  += __shfl_down(s, o, 64);
        ss += __shfl_down(ss, o, 64);
    }
    __syncthreads();   // protect red[] from any previous use
    if ((tid & 63) == 0) {
        red[(tid >> 6) * 2 + 0] = s;
        red[(tid >> 6) * 2 + 1] = ss;
    }
    __syncthreads();
    float rs = 0.f, rss = 0.f;
#pragma unroll
    for (int wv = 0; wv < MT / 64; ++wv) {
        rs  += red[wv * 2 + 0];
        rss += red[wv * 2 + 1];
    }
    return make_float2(rs, rss);
}

__global__ __launch_bounds__(MT) void mid_kernel(
    const float* __restrict__ p0,
    const float* __restrict__ ln0w, const float* __restrict__ ln0b,
    const float* __restrict__ w0,                       // [C,49] depthwise taps
    const float* __restrict__ ln1w, const float* __restrict__ ln1b,
    float* __restrict__ ker)                            // [B, C*49] out
{
    __shared__ float sA[CKK];   // 37.6 KB (stays under 64 KB static limit)
    __shared__ float red[16];
    int b = blockIdx.x;
    int tid = threadIdx.x;
    const float* src = p0 + (size_t)b * CKK;

    // ---- load + LN0 stats ----
    float s = 0.f, ss = 0.f;
    for (int i = tid; i < CKK; i += MT) {
        float v = src[i];
        sA[i] = v;
        s += v; ss += v * v;
    }
    float2 t0 = block_reduce2(s, ss, red, tid);
    float mean = t0.x * (1.f / CKK);
    float rstd = rsqrtf(t0.y * (1.f / CKK) - mean * mean + 1e-5f);

    // ---- normalize in place (each thread touches only its own indices) ----
    for (int i = tid; i < CKK; i += MT) {
        sA[i] = (sA[i] - mean) * rstd * ln0w[i] + ln0b[i];
    }
    __syncthreads();

    // ---- depthwise 7x7 SAME conv on the 7x7 map; outputs stay in registers ----
    float cv[MIT];
    float s2 = 0.f, ss2 = 0.f;
#pragma unroll
    for (int it = 0; it < MIT; ++it) {
        int idx = it * MT + tid;
        float acc = 0.f;
        if (idx < CKK) {
            int c  = idx / KK;
            int r  = idx - c * KK;
            int i0 = r / KS;
            int j0 = r - i0 * KS;
            const float* a  = sA + c * KK;
            const float* wc = w0 + c * KK;
#pragma unroll
            for (int u = 0; u < KS; ++u) {
                int ii = i0 + u - 3;
                if (ii < 0 || ii >= KS) continue;
#pragma unroll
                for (int v = 0; v < KS; ++v) {
                    int jj = j0 + v - 3;
                    if (jj < 0 || jj >= KS) continue;
                    acc += a[ii * KS + jj] * wc[u * KS + v];
                }
            }
        }
        cv[it] = acc;           // acc == 0 for tail lanes -> contributes 0
        s2 += acc; ss2 += acc * acc;
    }

    // ---- LN1 + ReLU -> dynamic kernels ----
    float2 t1 = block_reduce2(s2, ss2, red, tid);
    float m1    = t1.x * (1.f / CKK);
    float rstd1 = rsqrtf(t1.y * (1.f / CKK) - m1 * m1 + 1e-5f);
    float* dst = ker + (size_t)b * CKK;
#pragma unroll
    for (int it = 0; it < MIT; ++it) {
        int idx = it * MT + tid;
        if (idx < CKK) {
            float v = (cv[it] - m1) * rstd1 * ln1w[idx] + ln1b[idx];
            dst[idx] = v > 0.f ? v : 0.f;
        }
    }
}

// ---------------------------------------------------------------------------
// Kernel 3: per-(b,c) depthwise 7x7 SAME conv of ker[b,c] over x[b,c] (56x56)
// One block per (b,c). 56x56 tile in LDS, 49 taps in registers, each thread
// computes 4 consecutive outputs (7x10 window reads feed 4x49 FMAs).
// ---------------------------------------------------------------------------
__global__ __launch_bounds__(256) void conv_kernel(const float* __restrict__ x,
                                                   const float* __restrict__ ker,
                                                   float* __restrict__ out) {
    __shared__ float tile[HW];   // 12.25 KB
    __shared__ float kk[KK];
    int bc  = blockIdx.x;
    int tid = threadIdx.x;
    const float* src = x + (size_t)bc * HW;

    for (int i = tid; i < HW / 4; i += 256) {
        ((float4*)tile)[i] = ((const float4*)src)[i];
    }
    if (tid < KK) kk[tid] = ker[(size_t)bc * KK + tid];
    __syncthreads();

    float kr[KK];
#pragma unroll
    for (int t = 0; t < KK; ++t) kr[t] = kk[t];

    // 14 quads per row x 56 rows = 784 quads; 256 threads -> ~3 each
    for (int q = tid; q < (WW / 4) * HH; q += 256) {
        int h   = q / (WW / 4);
        int w0c = (q - h * (WW / 4)) * 4;
        float acc0 = 0.f, acc1 = 0.f, acc2 = 0.f, acc3 = 0.f;
#pragma unroll
        for (int u = 0; u < KS; ++u) {
            int r = h + u - 3;
            if (r < 0 || r >= HH) continue;
            const float* row = tile + r * WW;
            float vals[10];
#pragma unroll
            for (int t = 0; t < 10; ++t) {
                int cc = w0c - 3 + t;
                vals[t] = (cc >= 0 && cc < WW) ? row[cc] : 0.f;
            }
#pragma unroll
            for (int v = 0; v < KS; ++v) {
                float kv = kr[u * KS + v];
                acc0 += vals[v + 0] * kv;
                acc1 += vals[v + 1] * kv;
                acc2 += vals[v + 2] * kv;
                acc3 += vals[v + 3] * kv;
            }
        }
        float4 o = make_float4(acc0, acc1, acc2, acc3);
        *(float4*)(out + (size_t)bc * HW + h * WW + w0c) = o;
    }
}

// ---------------------------------------------------------------------------
extern "C" void kernel_launch(void* const* d_in, const int* in_sizes, int n_in,
                              void* d_out, int out_size, void* d_ws, size_t ws_size,
                              hipStream_t stream) {
    const float* x    = (const float*)d_in[0];
    const float* ln0w = (const float*)d_in[1];
    const float* ln0b = (const float*)d_in[2];
    const float* w0   = (const float*)d_in[3];
    const float* ln1w = (const float*)d_in[4];
    const float* ln1b = (const float*)d_in[5];
    float* out = (float*)d_out;

    float* p0  = (float*)d_ws;        // [B*C*49] pooled
    float* ker = p0 + NCELL;          // [B*C*49] dynamic kernels (2.4 MB total)

    pool_kernel<<<(NCELL + 255) / 256, 256, 0, stream>>>(x, p0);
    mid_kernel<<<BB, MT, 0, stream>>>(p0, ln0w, ln0b, w0, ln1w, ln1b, ker);
    conv_kernel<<<NBC, 256, 0, stream>>>(x, ker, out);
}